// Round 3
// baseline (967.909 us; speedup 1.0000x reference)
//
#include <hip/hip_runtime.h>

#define HASH_SIZE 256
#define OFFSET_SIZE 64
#define FEAT 8
#define QPT 4  // queries per thread

// Native Clang vector types: __builtin_nontemporal_* requires these
// (HIP_vector_type int4/float4 are classes and are rejected).
typedef int   vint4   __attribute__((ext_vector_type(4)));
typedef float vfloat4 __attribute__((ext_vector_type(4)));

// 4 queries per thread: 4 independent (coords -> offset-gather -> hash-gather)
// chains in flight per thread for memory-level parallelism.
// Coords for 4 consecutive queries = 48B = 3x int4, 16B-aligned for every i.
// Output for 4 queries = 128B contiguous, written with nontemporal float4.
__global__ void __launch_bounds__(256)
psh_kernel(const int* __restrict__ coords,
           const float* __restrict__ hash_table,
           const int* __restrict__ offset_table,
           const float* __restrict__ m0,
           const float* __restrict__ m1,
           float* __restrict__ out,
           int n) {
    int t = blockIdx.x * blockDim.x + threadIdx.x;
    int q0 = t * QPT;
    if (q0 >= n) return;

    float m0x = m0[0], m0y = m0[1], m0z = m0[2];
    float m1x = m1[0], m1y = m1[1], m1z = m1[2];

    // ---- coords: 3 x int4 nontemporal vector loads (stream-once data) ----
    const vint4* cp = (const vint4*)(coords + (size_t)q0 * 3);
    vint4 ca = __builtin_nontemporal_load(cp + 0);
    vint4 cb = __builtin_nontemporal_load(cp + 1);
    vint4 cc = __builtin_nontemporal_load(cp + 2);

    int cx[QPT], cy[QPT], cz[QPT];
    cx[0] = ca.x; cy[0] = ca.y; cz[0] = ca.z;
    cx[1] = ca.w; cy[1] = cb.x; cz[1] = cb.y;
    cx[2] = cb.z; cy[2] = cb.w; cz[2] = cc.x;
    cx[3] = cc.y; cy[3] = cc.z; cz[3] = cc.w;

    // ---- phase 1: all 4 offset-table gathers issued back-to-back ----
    size_t ooff[QPT];
#pragma unroll
    for (int q = 0; q < QPT; ++q) {
        int ox = ((int)((float)cx[q] * m1x)) & (OFFSET_SIZE - 1);
        int oy = ((int)((float)cy[q] * m1y)) & (OFFSET_SIZE - 1);
        int oz = ((int)((float)cz[q] * m1z)) & (OFFSET_SIZE - 1);
        ooff[q] = ((size_t)((ox * OFFSET_SIZE + oy) * OFFSET_SIZE + oz)) * 3;
    }
    int dx[QPT], dy[QPT], dz[QPT];
#pragma unroll
    for (int q = 0; q < QPT; ++q) {
        dx[q] = offset_table[ooff[q] + 0];
        dy[q] = offset_table[ooff[q] + 1];
        dz[q] = offset_table[ooff[q] + 2];
    }

    // ---- phase 2: all 8 hash-table float4 gathers issued back-to-back ----
    const float4* hp[QPT];
#pragma unroll
    for (int q = 0; q < QPT; ++q) {
        int hx = (((int)((float)cx[q] * m0x)) + dx[q]) & (HASH_SIZE - 1);
        int hy = (((int)((float)cy[q] * m0y)) + dy[q]) & (HASH_SIZE - 1);
        int hz = (((int)((float)cz[q] * m0z)) + dz[q]) & (HASH_SIZE - 1);
        size_t hoff = (((size_t)hx * HASH_SIZE + hy) * HASH_SIZE + hz) * FEAT;
        hp[q] = (const float4*)(hash_table + hoff);
    }
    float4 f0[QPT], f1[QPT];
#pragma unroll
    for (int q = 0; q < QPT; ++q) {
        f0[q] = hp[q][0];
        f1[q] = hp[q][1];
    }

    // ---- output: 128B contiguous, nontemporal (stream-once) ----
    vfloat4* op = (vfloat4*)(out + (size_t)q0 * FEAT);
#pragma unroll
    for (int q = 0; q < QPT; ++q) {
        vfloat4 v0 = {f0[q].x, f0[q].y, f0[q].z, f0[q].w};
        vfloat4 v1 = {f1[q].x, f1[q].y, f1[q].z, f1[q].w};
        __builtin_nontemporal_store(v0, op + 2 * q + 0);
        __builtin_nontemporal_store(v1, op + 2 * q + 1);
    }
}

extern "C" void kernel_launch(void* const* d_in, const int* in_sizes, int n_in,
                              void* d_out, int out_size, void* d_ws, size_t ws_size,
                              hipStream_t stream) {
    const int*   coords       = (const int*)d_in[0];
    const float* hash_table   = (const float*)d_in[1];
    const int*   offset_table = (const int*)d_in[2];
    const float* m0           = (const float*)d_in[3];
    const float* m1           = (const float*)d_in[4];
    float*       out          = (float*)d_out;

    int n = in_sizes[0] / 3;               // 4,000,000 queries
    int nthreads = (n + QPT - 1) / QPT;    // 1,000,000 threads
    int block = 256;
    int grid = (nthreads + block - 1) / block;
    psh_kernel<<<grid, block, 0, stream>>>(coords, hash_table, offset_table,
                                           m0, m1, out, n);
}